// Round 15
// baseline (93.169 us; speedup 1.0000x reference)
//
#include <hip/hip_runtime.h>

// CARAFE: x [4,256,64,64] f32, kernel [4,25,128,128] f32 -> out [4,256,128,128] f32
// out[b,c,2h+p,2w+q] = sum_{ki,kj} x[b,c,h+ki-2,w+kj-2] * kern[b,ki*5+kj,2h+p,2w+q]
//
// R14: occupancy probe done right. Ledger: ~30us invariant under occupancy
// 3->5 w/SIMD, store order, LDS->L1 (-25%), LDS-amortization 2x, packed-FMA
// (R13: SPILLED, VGPR 64 + 66MB scratch fetch -> never force launch_bounds
// below live state). Pipe model says ideal ~12-14us; wall = latency stalls at
// 4-6 waves/SIMD. Here: 512-thread blocks share ONE 25.6KB weight slab across
// 64 ch -> LDS no longer caps blocks/CU; (512,6) = 6 waves/SIMD, VGPR cap 85
// fits the proven R8 tile (4ch x 2col, scalar acc ~80 VGPR). Keep: v4 weight
// staging (R12), plain v4 stores (R6: NT sub-line = 17x ECC-RMW), cc-fast
// XCD chunking, aligned-v2 x windows, block-uniform edge-row skip.

typedef float v2 __attribute__((ext_vector_type(2)));
typedef float v4 __attribute__((ext_vector_type(4)));

__global__ __launch_bounds__(512, 6)
void carafe_kernel(const float* __restrict__ x,
                   const float* __restrict__ kern,
                   float* __restrict__ out) {
    __shared__ __align__(16) float wt[25 * 256];   // [k][p][ow] for rows {2h,2h+1}

    // XCD-chunked swizzle: 1024 blocks, 128 per XCD (cc fast within a chunk).
    const int raw = blockIdx.x;
    const int l   = (raw & 7) * 128 + (raw >> 3);
    const int cc  = l & 3;           // 64-channel chunk
    const int h   = (l >> 2) & 63;   // input row
    const int b   = l >> 8;          // batch
    const int tid = threadIdx.x;
    const int t   = tid & 31;        // col group: input cols 2t,2t+1 -> out 4t..4t+3
    const int g   = tid >> 5;        // ch group: 16 groups x 4 channels
    const int c0  = cc * 64 + g * 4;

    // ---- stage weights (25.6KB) as v4: 1600 v4 loads over 512 threads ----
    {
        const float* kbase = kern + (size_t)b * 25 * 16384 + (size_t)(2 * h) * 128;
        for (int idx = tid; idx < 1600; idx += 512) {
            const int f = idx * 4;           // flat float index in wt
            const int k = f >> 8;
            const int r = f & 255;           // p*128 + ow  (rows 2h,2h+1 contiguous)
            *(v4*)&wt[f] = *(const v4*)(kbase + (size_t)k * 16384 + r);
        }
    }
    __syncthreads();

    float acc[4][2][2][2] = {};      // [ch][cj][p][q]
    const float* xb = x + (size_t)(b * 256 + c0) * 4096;

#pragma unroll
    for (int ki = 0; ki < 5; ++ki) {
        const int gr = h + ki - 2;
        if ((unsigned)gr >= 64u) continue;     // block-uniform zero-pad rows

        // x window per ch: cols 2t-2 .. 2t+3 via 3 aligned v2 loads
        float xw[4][6];
#pragma unroll
        for (int ch = 0; ch < 4; ++ch) {
            const float* rowp = xb + (size_t)ch * 4096 + gr * 64;
            const v2 A = *(const v2*)(rowp + (t ? 2 * t - 2 : 0));
            const v2 B = *(const v2*)(rowp + 2 * t);
            const v2 C = *(const v2*)(rowp + (t < 31 ? 2 * t + 2 : 60));
            xw[ch][0] = t ? A.x : 0.0f;            // col 2t-2
            xw[ch][1] = t ? A.y : 0.0f;            // col 2t-1
            xw[ch][2] = B.x;  xw[ch][3] = B.y;     // cols 2t, 2t+1
            xw[ch][4] = (t < 31) ? C.x : 0.0f;     // col 2t+2
            xw[ch][5] = (t < 31) ? C.y : 0.0f;     // col 2t+3
        }

#pragma unroll
        for (int kj = 0; kj < 5; ++kj) {
            const int k = ki * 5 + kj;
            const v4 w0 = *(const v4*)&wt[k * 256 + 4 * t];        // p=0, ow 4t..4t+3
            const v4 w1 = *(const v4*)&wt[k * 256 + 128 + 4 * t];  // p=1
#pragma unroll
            for (int ch = 0; ch < 4; ++ch) {
#pragma unroll
                for (int cj = 0; cj < 2; ++cj) {
                    const float xv = xw[ch][cj + kj];
                    acc[ch][cj][0][0] += w0[2 * cj]     * xv;
                    acc[ch][cj][0][1] += w0[2 * cj + 1] * xv;
                    acc[ch][cj][1][0] += w1[2 * cj]     * xv;
                    acc[ch][cj][1][1] += w1[2 * cj + 1] * xv;
                }
            }
        }
    }

    // ---- stores: 1 v4 per (ch,p); lanes t=0..31 cover a contiguous 512B row ----
#pragma unroll
    for (int ch = 0; ch < 4; ++ch) {
        float* ob = out + ((size_t)(b * 256 + c0 + ch) * 128 + 2 * h) * 128 + 4 * t;
#pragma unroll
        for (int p = 0; p < 2; ++p) {
            v4 s;
            s.x = acc[ch][0][p][0]; s.y = acc[ch][0][p][1];
            s.z = acc[ch][1][p][0]; s.w = acc[ch][1][p][1];
            *(v4*)(ob + p * 128) = s;
        }
    }
}

extern "C" void kernel_launch(void* const* d_in, const int* in_sizes, int n_in,
                              void* d_out, int out_size, void* d_ws, size_t ws_size,
                              hipStream_t stream) {
    const float* x    = (const float*)d_in[0];
    const float* kern = (const float*)d_in[1];
    float* out        = (float*)d_out;
    // grid: b(4) * h(64) * cc(4) = 1024 blocks of 512 threads
    carafe_kernel<<<dim3(1024), dim3(512), 0, stream>>>(x, kern, out);
}

// Round 17
// 48.798 us; speedup vs baseline: 1.9093x; 1.9093x over previous
//
#include <hip/hip_runtime.h>

// CARAFE: x [4,256,64,64] f32, kernel [4,25,128,128] f32 -> out [4,256,128,128] f32
// out[b,c,2h+p,2w+q] = sum_{ki,kj} x[b,c,h+ki-2,w+kj-2] * kern[b,ki*5+kj,2h+p,2w+q]
//
// R16: latency-depth design. Evidence: R7/R8/R10/R12 all ~30us with W(waves) x
// D(mem-depth) ~constant; no pipe >50% busy -> latency-bound. R13/R14: forcing
// occupancy via launch_bounds spills (VGPR 40-64 + 200MB scratch) -> NEVER set
// min-waves below live state. Here D is maximized instead of W: ALL 25 weight
// v4s preloaded into registers (independent, one vmcnt burst), NO LDS, NO
// barrier; p split across blocks so weights fit (100 VGPR). Row loop has only
// 12 independent v2 x-loads + FMA. launch_bounds(256) flat only -> VGPR free
// to ~256, no spill. Keep: plain v4 stores (R6: NT sub-line = 17x ECC-RMW),
// XCD-chunked bid swizzle, aligned-v2 x windows, block-uniform edge-row skip.

typedef float v2 __attribute__((ext_vector_type(2)));
typedef float v4 __attribute__((ext_vector_type(4)));

__global__ __launch_bounds__(256)
void carafe_kernel(const float* __restrict__ x,
                   const float* __restrict__ kern,
                   float* __restrict__ out) {
    // 4096 blocks, XCD-chunked: 512 consecutive logical ids per XCD.
    const int raw = blockIdx.x;
    const int l   = (raw & 7) * 512 + (raw >> 3);
    const int p   = l & 1;           // output sub-row (fastest: p-pair shares x)
    const int cc  = (l >> 1) & 7;    // 32-channel chunk
    const int h   = (l >> 4) & 63;   // input row
    const int b   = l >> 10;         // batch
    const int tid = threadIdx.x;
    const int t   = tid & 31;        // out cols 4t..4t+3 (input cols 2t,2t+1)
    const int g   = tid >> 5;        // 8 groups x 4 channels
    const int c0  = cc * 32 + g * 4;
    const int oh  = 2 * h + p;

    // ---- preload ALL 25 weight v4s into registers: independent, deep vmcnt ----
    const float* kb = kern + (size_t)b * 25 * 16384 + (size_t)oh * 128 + 4 * t;
    v4 wv[25];
#pragma unroll
    for (int k = 0; k < 25; ++k)
        wv[k] = *(const v4*)(kb + (size_t)k * 16384);

    float acc[4][4] = {};            // [ch][out col j]
    const float* xb = x + (size_t)(b * 256 + c0) * 4096;

#pragma unroll
    for (int ki = 0; ki < 5; ++ki) {
        const int gr = h + ki - 2;
        if ((unsigned)gr >= 64u) continue;     // block-uniform zero-pad rows

        // x window per ch: cols 2t-2 .. 2t+3 via 3 aligned v2 loads (independent)
        float xw[4][6];
#pragma unroll
        for (int ch = 0; ch < 4; ++ch) {
            const float* rowp = xb + (size_t)ch * 4096 + gr * 64;
            const v2 A = *(const v2*)(rowp + (t ? 2 * t - 2 : 0));
            const v2 B = *(const v2*)(rowp + 2 * t);
            const v2 C = *(const v2*)(rowp + (t < 31 ? 2 * t + 2 : 60));
            xw[ch][0] = t ? A.x : 0.0f;            // col 2t-2
            xw[ch][1] = t ? A.y : 0.0f;            // col 2t-1
            xw[ch][2] = B.x;  xw[ch][3] = B.y;     // cols 2t, 2t+1
            xw[ch][4] = (t < 31) ? C.x : 0.0f;     // col 2t+2
            xw[ch][5] = (t < 31) ? C.y : 0.0f;     // col 2t+3
        }

#pragma unroll
        for (int kj = 0; kj < 5; ++kj) {
            const v4 w = wv[ki * 5 + kj];          // registers — no memory op
#pragma unroll
            for (int ch = 0; ch < 4; ++ch) {
                const float xlo = xw[ch][kj];      // out cols 4t,4t+1 (iw=2t)
                const float xhi = xw[ch][kj + 1];  // out cols 4t+2,4t+3 (iw=2t+1)
                acc[ch][0] += w.x * xlo;
                acc[ch][1] += w.y * xlo;
                acc[ch][2] += w.z * xhi;
                acc[ch][3] += w.w * xhi;
            }
        }
    }

    // ---- stores: 1 v4 per ch; lanes t=0..31 cover a contiguous 512B row ----
#pragma unroll
    for (int ch = 0; ch < 4; ++ch) {
        float* ob = out + ((size_t)(b * 256 + c0 + ch) * 128 + oh) * 128 + 4 * t;
        v4 s;
        s.x = acc[ch][0]; s.y = acc[ch][1]; s.z = acc[ch][2]; s.w = acc[ch][3];
        *(v4*)ob = s;
    }
}

extern "C" void kernel_launch(void* const* d_in, const int* in_sizes, int n_in,
                              void* d_out, int out_size, void* d_ws, size_t ws_size,
                              hipStream_t stream) {
    const float* x    = (const float*)d_in[0];
    const float* kern = (const float*)d_in[1];
    float* out        = (float*)d_out;
    // grid: b(4) * h(64) * cc(8) * p(2) = 4096 blocks of 256 threads
    carafe_kernel<<<dim3(4096), dim3(256), 0, stream>>>(x, kern, out);
}

// Round 18
// 30.645 us; speedup vs baseline: 3.0403x; 1.5924x over previous
//
#include <hip/hip_runtime.h>

// CARAFE: x [4,256,64,64] f32, kernel [4,25,128,128] f32 -> out [4,256,128,128] f32
// out[b,c,2h+p,2w+q] = sum_{ki,kj} x[b,c,h+ki-2,w+kj-2] * kern[b,ki*5+kj,2h+p,2w+q]
//
// R18: single-round resident grid. Ledger: ~30us invariant under occupancy,
// store order, LDS<->L1 weights, LDS amortization, packed-FMA (spill), reg
// preload (compiler sinks). Pipe-sum ~34us vs observed 29 -> pipes don't
// overlap; untouched suspect = dispatch rounds + per-block staging barrier
// stall (2048 blocks / ~5 resident = 1.6 rounds; every block opens with a
// 25.6KB stage + barrier nothing hides). Here: grid 1024 = EXACTLY 4 blocks/CU
// (VGPR 96 -> 4 waves/SIMD, LDS 102.4KB/CU) -> all blocks resident at t=0,
// zero rounds; block = (b,h,ccpair) stages weights ONCE, computes 2 cc chunks.
// Compute tile is literal R8 (best: 29.3us, 96 VGPR, no spill under (256,4)).
// Keep: v4 weight staging, plain v4 stores (R6: NT sub-line = 17x ECC-RMW),
// XCD-chunked swizzle, aligned-v2 x windows, block-uniform edge-row skip.

typedef float v2 __attribute__((ext_vector_type(2)));
typedef float v4 __attribute__((ext_vector_type(4)));

__global__ __launch_bounds__(256, 4)
void carafe_kernel(const float* __restrict__ x,
                   const float* __restrict__ kern,
                   float* __restrict__ out) {
    __shared__ __align__(16) float wt[25 * 256];   // [k][p][ow] for rows {2h,2h+1}

    // XCD-chunked swizzle: 1024 blocks, 128 per XCD.
    const int raw = blockIdx.x;
    const int l   = (raw & 7) * 128 + (raw >> 3);
    const int ccp = l & 3;           // cc pair: chunks {ccp, ccp+4}
    const int h   = (l >> 2) & 63;   // input row
    const int b   = l >> 8;          // batch
    const int tid = threadIdx.x;
    const int t   = tid & 31;        // col group: input cols 2t,2t+1 -> out 4t..4t+3
    const int g   = tid >> 5;        // 8 groups x 4 channels

    // ---- stage weights (25.6KB) ONCE for both cc chunks ----
    {
        const float* kbase = kern + (size_t)b * 25 * 16384 + (size_t)(2 * h) * 128;
        for (int idx = tid; idx < 1600; idx += 256) {
            const int f = idx * 4;           // flat float index in wt
            const int k = f >> 8;
            const int r = f & 255;           // p*128 + ow (rows 2h,2h+1 contiguous)
            *(v4*)&wt[f] = *(const v4*)(kbase + (size_t)k * 16384 + r);
        }
    }
    __syncthreads();

    // ---- two channel-chunk items share the staged slab ----
#pragma unroll
    for (int it = 0; it < 2; ++it) {
        const int cc = ccp + it * 4;
        const int c0 = cc * 32 + g * 4;
        const float* xb = x + (size_t)(b * 256 + c0) * 4096;

        float acc[4][2][2][2] = {};      // [ch][cj][p][q]

#pragma unroll
        for (int ki = 0; ki < 5; ++ki) {
            const int gr = h + ki - 2;
            if ((unsigned)gr >= 64u) continue;     // block-uniform zero-pad rows

            // x window per ch: cols 2t-2 .. 2t+3 via 3 aligned v2 loads
            float xw[4][6];
#pragma unroll
            for (int ch = 0; ch < 4; ++ch) {
                const float* rowp = xb + (size_t)ch * 4096 + gr * 64;
                const v2 A = *(const v2*)(rowp + (t ? 2 * t - 2 : 0));
                const v2 B = *(const v2*)(rowp + 2 * t);
                const v2 C = *(const v2*)(rowp + (t < 31 ? 2 * t + 2 : 60));
                xw[ch][0] = t ? A.x : 0.0f;            // col 2t-2
                xw[ch][1] = t ? A.y : 0.0f;            // col 2t-1
                xw[ch][2] = B.x;  xw[ch][3] = B.y;     // cols 2t, 2t+1
                xw[ch][4] = (t < 31) ? C.x : 0.0f;     // col 2t+2
                xw[ch][5] = (t < 31) ? C.y : 0.0f;     // col 2t+3
            }

#pragma unroll
            for (int kj = 0; kj < 5; ++kj) {
                const int k = ki * 5 + kj;
                const v4 w0 = *(const v4*)&wt[k * 256 + 4 * t];        // p=0
                const v4 w1 = *(const v4*)&wt[k * 256 + 128 + 4 * t];  // p=1
#pragma unroll
                for (int ch = 0; ch < 4; ++ch) {
#pragma unroll
                    for (int cj = 0; cj < 2; ++cj) {
                        const float xv = xw[ch][cj + kj];
                        acc[ch][cj][0][0] += w0[2 * cj]     * xv;
                        acc[ch][cj][0][1] += w0[2 * cj + 1] * xv;
                        acc[ch][cj][1][0] += w1[2 * cj]     * xv;
                        acc[ch][cj][1][1] += w1[2 * cj + 1] * xv;
                    }
                }
            }
        }

        // ---- stores: 1 v4 per (ch,p); lanes t=0..31 cover contiguous 512B ----
#pragma unroll
        for (int ch = 0; ch < 4; ++ch) {
            float* ob = out + ((size_t)(b * 256 + c0 + ch) * 128 + 2 * h) * 128 + 4 * t;
#pragma unroll
            for (int p = 0; p < 2; ++p) {
                v4 s;
                s.x = acc[ch][0][p][0]; s.y = acc[ch][0][p][1];
                s.z = acc[ch][1][p][0]; s.w = acc[ch][1][p][1];
                *(v4*)(ob + p * 128) = s;
            }
        }
    }
}

extern "C" void kernel_launch(void* const* d_in, const int* in_sizes, int n_in,
                              void* d_out, int out_size, void* d_ws, size_t ws_size,
                              hipStream_t stream) {
    const float* x    = (const float*)d_in[0];
    const float* kern = (const float*)d_in[1];
    float* out        = (float*)d_out;
    // grid: b(4) * h(64) * ccpair(4) = 1024 blocks of 256 threads = 4 blocks/CU
    carafe_kernel<<<dim3(1024), dim3(256), 0, stream>>>(x, kern, out);
}

// Round 19
// 30.420 us; speedup vs baseline: 3.0627x; 1.0074x over previous
//
#include <hip/hip_runtime.h>

// CARAFE: x [4,256,64,64] f32, kernel [4,25,128,128] f32 -> out [4,256,128,128] f32
// out[b,c,2h+p,2w+q] = sum_{ki,kj} x[b,c,h+ki-2,w+kj-2] * kern[b,ki*5+kj,2h+p,2w+q]
//
// R19: x-row software pipeline on the R8 champion (29.3us). Null ledger:
// occupancy x2, store order, LDS<->L1 weights, LDS amort 2x, packed-FMA
// (spill), reg preload (sunk), single-round grid. Untested: per-row x-load
// latency (12 dependent v2 loads head each row, ~200-400cy, unhidden at ~2
// eff waves/SIMD). Fix: double-buffered x windows (static named bufs, rule
// #20), row ki+1 loads issued before row ki taps; row-0 loads issued BEFORE
// the staging barrier (independent of LDS). Loads use clamped row addresses
// (always legal), tap loop keeps the block-uniform validity skip. (256,3):
// ~170 VGPR cap >> ~125 live (R13/R14 lesson: never cap below live state).
// Keep: 25.6KB weight LDS, v4 staging, plain v4 stores (R6: NT sub-line =
// 17x ECC-RMW), cc-fast XCD chunk swizzle, aligned-v2 x windows.

typedef float v2 __attribute__((ext_vector_type(2)));
typedef float v4 __attribute__((ext_vector_type(4)));

#define LOADROW(BUF, KI)                                                       \
    {                                                                          \
        int gr_ = h + (KI) - 2;                                                \
        gr_ = gr_ < 0 ? 0 : (gr_ > 63 ? 63 : gr_);                             \
        _Pragma("unroll")                                                      \
        for (int ch = 0; ch < 4; ++ch) {                                       \
            const float* rowp = xb + (size_t)ch * 4096 + gr_ * 64;             \
            const v2 A = *(const v2*)(rowp + (t ? 2 * t - 2 : 0));             \
            const v2 B = *(const v2*)(rowp + 2 * t);                           \
            const v2 C = *(const v2*)(rowp + (t < 31 ? 2 * t + 2 : 60));       \
            BUF[ch][0] = t ? A.x : 0.0f;                                       \
            BUF[ch][1] = t ? A.y : 0.0f;                                       \
            BUF[ch][2] = B.x;  BUF[ch][3] = B.y;                               \
            BUF[ch][4] = (t < 31) ? C.x : 0.0f;                                \
            BUF[ch][5] = (t < 31) ? C.y : 0.0f;                                \
        }                                                                      \
    }

#define TAPS(BUF, KI)                                                          \
    if ((unsigned)(h + (KI) - 2) < 64u) {                                      \
        _Pragma("unroll")                                                      \
        for (int kj = 0; kj < 5; ++kj) {                                       \
            const int k = (KI) * 5 + kj;                                       \
            const v4 w0 = *(const v4*)&wt[k * 256 + 4 * t];                    \
            const v4 w1 = *(const v4*)&wt[k * 256 + 128 + 4 * t];              \
            _Pragma("unroll")                                                  \
            for (int ch = 0; ch < 4; ++ch) {                                   \
                _Pragma("unroll")                                              \
                for (int cj = 0; cj < 2; ++cj) {                               \
                    const float xv = BUF[ch][cj + kj];                         \
                    acc[ch][cj][0][0] += w0[2 * cj]     * xv;                  \
                    acc[ch][cj][0][1] += w0[2 * cj + 1] * xv;                  \
                    acc[ch][cj][1][0] += w1[2 * cj]     * xv;                  \
                    acc[ch][cj][1][1] += w1[2 * cj + 1] * xv;                  \
                }                                                              \
            }                                                                  \
        }                                                                      \
    }

__global__ __launch_bounds__(256, 3)
void carafe_kernel(const float* __restrict__ x,
                   const float* __restrict__ kern,
                   float* __restrict__ out) {
    __shared__ __align__(16) float wt[25 * 256];   // [k][p][ow] for rows {2h,2h+1}

    // XCD-chunked swizzle: 2048 blocks, 256 per XCD (cc fast within a chunk).
    const int raw = blockIdx.x;
    const int l   = (raw & 7) * 256 + (raw >> 3);
    const int cc  = l & 7;           // 32-channel chunk
    const int h   = (l >> 3) & 63;   // input row
    const int b   = l >> 9;          // batch
    const int tid = threadIdx.x;
    const int t   = tid & 31;        // col group: input cols 2t,2t+1 -> out 4t..4t+3
    const int g   = tid >> 5;        // 8 groups x 4 channels
    const int c0  = cc * 32 + g * 4;

    const float* xb = x + (size_t)(b * 256 + c0) * 4096;

    // ---- stage weights (25.6KB) as v4, coalesced ----
    {
        const float* kbase = kern + (size_t)b * 25 * 16384 + (size_t)(2 * h) * 128;
        for (int idx = tid; idx < 1600; idx += 256) {
            const int f = idx * 4;           // flat float index in wt
            const int k = f >> 8;
            const int r = f & 255;           // p*128 + ow (rows 2h,2h+1 contiguous)
            *(v4*)&wt[f] = *(const v4*)(kbase + (size_t)k * 16384 + r);
        }
    }

    float acc[4][2][2][2] = {};      // [ch][cj][p][q]
    float xwa[4][6], xwb[4][6];      // double-buffered x windows (static names)

    LOADROW(xwa, 0);                 // row-0 prefetch hides under the barrier
    __syncthreads();

    LOADROW(xwb, 1);  TAPS(xwa, 0);
    LOADROW(xwa, 2);  TAPS(xwb, 1);
    LOADROW(xwb, 3);  TAPS(xwa, 2);
    LOADROW(xwa, 4);  TAPS(xwb, 3);
                      TAPS(xwa, 4);

    // ---- stores: 1 v4 per (ch,p); lanes t=0..31 cover a contiguous 512B row ----
#pragma unroll
    for (int ch = 0; ch < 4; ++ch) {
        float* ob = out + ((size_t)(b * 256 + c0 + ch) * 128 + 2 * h) * 128 + 4 * t;
#pragma unroll
        for (int p = 0; p < 2; ++p) {
            v4 s;
            s.x = acc[ch][0][p][0]; s.y = acc[ch][0][p][1];
            s.z = acc[ch][1][p][0]; s.w = acc[ch][1][p][1];
            *(v4*)(ob + p * 128) = s;
        }
    }
}

extern "C" void kernel_launch(void* const* d_in, const int* in_sizes, int n_in,
                              void* d_out, int out_size, void* d_ws, size_t ws_size,
                              hipStream_t stream) {
    const float* x    = (const float*)d_in[0];
    const float* kern = (const float*)d_in[1];
    float* out        = (float*)d_out;
    // grid: b(4) * h(64) * cc(8) = 2048 blocks of 256 threads
    carafe_kernel<<<dim3(2048), dim3(256), 0, stream>>>(x, kern, out);
}